// Round 11
// baseline (516.341 us; speedup 1.0000x reference)
//
#include <hip/hip_runtime.h>
#include <hip/hip_bf16.h>

#define EMBED 128
#define NRAD  16
#define OUTE  256

typedef __bf16 bf16x8 __attribute__((ext_vector_type(8)));
typedef float  f32x4  __attribute__((ext_vector_type(4)));

static __device__ __forceinline__ unsigned short f2bf(float x) {
    return __builtin_bit_cast(unsigned short, (__bf16)x);
}

// ---------------------------------------------------------------------------
// Phase 0: fast zero-fill of summed+counts (adjacent in ws).
// ---------------------------------------------------------------------------
__global__ __launch_bounds__(256) void zero_fill_kernel(uint4* __restrict__ dst, int n4)
{
    const uint4 z = {0u, 0u, 0u, 0u};
    for (int i = blockIdx.x * blockDim.x + threadIdx.x; i < n4;
         i += gridDim.x * blockDim.x)
        dst[i] = z;
}

// ---------------------------------------------------------------------------
// Phase 1a: histogram of receiving-atom indices.
// ---------------------------------------------------------------------------
__global__ __launch_bounds__(256) void hist_kernel(const int* __restrict__ idx_i,
                                                   int* __restrict__ counts, int n_edges)
{
    for (int e = blockIdx.x * blockDim.x + threadIdx.x; e < n_edges;
         e += gridDim.x * blockDim.x)
        atomicAdd(&counts[idx_i[e]], 1);
}

// ---------------------------------------------------------------------------
// Phase 1b: single-block exclusive scan of counts -> cursor (bucket starts).
// ---------------------------------------------------------------------------
__global__ __launch_bounds__(1024) void scan_kernel(const int* __restrict__ counts,
                                                    int* __restrict__ cursor, int n)
{
    __shared__ int partial[1024];
    const int tid = threadIdx.x;
    const int chunk = (n + 1023) / 1024;
    const int lo = min(tid * chunk, n), hi = min(lo + chunk, n);
    int s = 0;
    for (int i = lo; i < hi; ++i) s += counts[i];
    partial[tid] = s;
    __syncthreads();
    for (int off = 1; off < 1024; off <<= 1) {
        int v = (tid >= off) ? partial[tid - off] : 0;
        __syncthreads();
        partial[tid] += v;
        __syncthreads();
    }
    int run = (tid > 0) ? partial[tid - 1] : 0;
    for (int i = lo; i < hi; ++i) {
        cursor[i] = run;
        run += counts[i];
    }
}

// ---------------------------------------------------------------------------
// Phase 1c: scatter edge ids into CSR order; record owning particle per pos.
// ---------------------------------------------------------------------------
__global__ __launch_bounds__(256) void scatter_ids_kernel(const int* __restrict__ idx_i,
                                                          int* __restrict__ cursor,
                                                          int* __restrict__ edge_order,
                                                          int* __restrict__ pid_sorted,
                                                          int n_edges)
{
    for (int e = blockIdx.x * blockDim.x + threadIdx.x; e < n_edges;
         e += gridDim.x * blockDim.x) {
        const int i = idx_i[e];
        const int pos = atomicAdd(&cursor[i], 1);
        edge_order[pos] = e;
        pid_sorted[pos] = i;
    }
}

// ---------------------------------------------------------------------------
// Phase 1d: windowed segmented reduction, R8 pipeline:
// - window's 64 edge ids / pids held in lanes (1 coalesced load each),
//   broadcast per chunk via __shfl (VALU only -> kills the id->data hop)
// - chunk q+4's msg/rbf loads issued BEFORE chunk q's SEGSTEP (issue-early /
//   consume-late); dot for q+4 computed after SEGSTEP of q
// - ALL pipeline state in individually-NAMED scalars (R5 lesson: demotable
//   arrays -> scratch -> 200 MB phantom HBM traffic)
// ---------------------------------------------------------------------------
__device__ __forceinline__ float2 rbf_dot(float4 q0, float4 q1, float4 q2, float4 q3,
                                          const float2* w)
{
    const float rv[NRAD] = {q0.x, q0.y, q0.z, q0.w, q1.x, q1.y, q1.z, q1.w,
                            q2.x, q2.y, q2.z, q2.w, q3.x, q3.y, q3.z, q3.w};
    float tx = 0.f, ty = 0.f;
#pragma unroll
    for (int r = 0; r < NRAD; ++r) {
        tx = fmaf(rv[r], w[r].x, tx);
        ty = fmaf(rv[r], w[r].y, ty);
    }
    return make_float2(tx, ty);
}

#define SEGSTEP(P, M, T)                                                    \
    do {                                                                    \
        if ((P) != cur) {                                                   \
            if (first) {                                                    \
                atomicAdd(&summed[(long long)cur * EMBED + col], ax);       \
                atomicAdd(&summed[(long long)cur * EMBED + col + 1], ay);   \
                first = false;                                              \
            } else {                                                        \
                *reinterpret_cast<float2*>(                                 \
                    &summed[(long long)cur * EMBED + col]) =                \
                    make_float2(ax, ay);                                    \
            }                                                               \
            ax = 0.f; ay = 0.f; cur = (P);                                  \
        }                                                                   \
        ax = fmaf((M).x, (T).x, ax);                                        \
        ay = fmaf((M).y, (T).y, ay);                                        \
    } while (0)

// prefetch helpers: J must be a literal token (0..3)
#define PREF_IDS(J)                                                         \
    eN##J = __shfl(myE, qn + J, 64);                                        \
    pN##J = __shfl(myP, qn + J, 64);

#define PREF_LOAD(J)                                                        \
    mN##J = *reinterpret_cast<const float2*>(                               \
        messages + (long long)eN##J * EMBED + col);                         \
    {                                                                       \
        const float4* R_ =                                                  \
            reinterpret_cast<const float4*>(rbf + (long long)eN##J * NRAD); \
        rA##J = R_[0]; rB##J = R_[1]; rC##J = R_[2]; rD##J = R_[3];         \
    }

#define PREF_DOT(J) tN##J = rbf_dot(rA##J, rB##J, rC##J, rD##J, w);

__global__ __launch_bounds__(256, 3) void gated_segsum_kernel(
    const float* __restrict__ messages, const float* __restrict__ rbf,
    const int* __restrict__ edge_order, const int* __restrict__ pid_sorted,
    const float* __restrict__ W_rbf, float* __restrict__ summed, int n_edges)
{
    const int lane = threadIdx.x & 63;
    const int wv   = threadIdx.x >> 6;
    const int col  = lane * 2;

    float2 w[NRAD];
#pragma unroll
    for (int r = 0; r < NRAD; ++r)
        w[r] = *reinterpret_cast<const float2*>(&W_rbf[r * EMBED + col]);

    const int nwin = (n_edges + 63) >> 6;
    for (int win = blockIdx.x * 4 + wv; win < nwin; win += gridDim.x * 4) {
        const int w0 = win << 6;
        const int nq = min(n_edges - w0, 64);

        float ax = 0.f, ay = 0.f;
        bool first = true;

        if (nq == 64) {
            // -------- fast path: full window, pipelined --------
            const int myE = edge_order[w0 + lane];
            const int myP = pid_sorted[w0 + lane];
            int cur = __shfl(myP, 0, 64);

            int eN0, eN1, eN2, eN3, pN0, pN1, pN2, pN3;
            float2 mN0, mN1, mN2, mN3, tN0, tN1, tN2, tN3;
            float4 rA0, rB0, rC0, rD0, rA1, rB1, rC1, rD1;
            float4 rA2, rB2, rC2, rD2, rA3, rB3, rC3, rD3;
            float2 m0, m1, m2, m3, t0, t1, t2, t3;
            int p0, p1, p2, p3;

            // prologue: chunk 0
            int qn = 0;
            PREF_IDS(0) PREF_IDS(1) PREF_IDS(2) PREF_IDS(3)
            PREF_LOAD(0) PREF_LOAD(1) PREF_LOAD(2) PREF_LOAD(3)
            PREF_DOT(0) PREF_DOT(1) PREF_DOT(2) PREF_DOT(3)
            m0 = mN0; m1 = mN1; m2 = mN2; m3 = mN3;
            t0 = tN0; t1 = tN1; t2 = tN2; t3 = tN3;
            p0 = pN0; p1 = pN1; p2 = pN2; p3 = pN3;

            for (int q = 0; q < 64; q += 4) {
                const bool more = (q + 4) < 64;
                if (more) {
                    qn = q + 4;
                    PREF_IDS(0) PREF_IDS(1) PREF_IDS(2) PREF_IDS(3)
                    PREF_LOAD(0) PREF_LOAD(1) PREF_LOAD(2) PREF_LOAD(3)
                }
                SEGSTEP(p0, m0, t0);
                SEGSTEP(p1, m1, t1);
                SEGSTEP(p2, m2, t2);
                SEGSTEP(p3, m3, t3);
                if (more) {
                    PREF_DOT(0) PREF_DOT(1) PREF_DOT(2) PREF_DOT(3)
                    m0 = mN0; m1 = mN1; m2 = mN2; m3 = mN3;
                    t0 = tN0; t1 = tN1; t2 = tN2; t3 = tN3;
                    p0 = pN0; p1 = pN1; p2 = pN2; p3 = pN3;
                }
            }
            atomicAdd(&summed[(long long)cur * EMBED + col], ax);
            atomicAdd(&summed[(long long)cur * EMBED + col + 1], ay);
        } else {
            // -------- tail window: simple path --------
            int cur = pid_sorted[w0];
            for (int q = 0; q < nq; ++q) {
                const int b = w0 + q;
                const int e = edge_order[b];
                const int p = pid_sorted[b];
                const float2 m = *reinterpret_cast<const float2*>(
                    messages + (long long)e * EMBED + col);
                const float4* R =
                    reinterpret_cast<const float4*>(rbf + (long long)e * NRAD);
                const float2 t = rbf_dot(R[0], R[1], R[2], R[3], w);
                SEGSTEP(p, m, t);
            }
            atomicAdd(&summed[(long long)cur * EMBED + col], ax);
            atomicAdd(&summed[(long long)cur * EMBED + col + 1], ay);
        }
    }
}

// ---------------------------------------------------------------------------
// Weight prep: cast + transpose to bf16 W^T [N][K].
// ---------------------------------------------------------------------------
__global__ __launch_bounds__(256) void prep_weights_kernel(
    const float* __restrict__ Wup, const float* __restrict__ W1,
    const float* __restrict__ W2, const float* __restrict__ W3,
    __bf16* __restrict__ WupT, __bf16* __restrict__ W1T,
    __bf16* __restrict__ W2T, __bf16* __restrict__ W3T)
{
    const int total = OUTE * EMBED + 3 * OUTE * OUTE;
    for (int id = blockIdx.x * blockDim.x + threadIdx.x; id < total;
         id += gridDim.x * blockDim.x) {
        if (id < OUTE * EMBED) {
            const int n = id / EMBED, k = id % EMBED;
            WupT[id] = (__bf16)Wup[k * OUTE + n];
        } else {
            const int r = id - OUTE * EMBED;
            const int wsel = r / (OUTE * OUTE);
            const int rr = r % (OUTE * OUTE);
            const int n = rr / OUTE, k = rr % OUTE;
            const float* src = (wsel == 0) ? W1 : ((wsel == 1) ? W2 : W3);
            __bf16* dst = (wsel == 0) ? W1T : ((wsel == 1) ? W2T : W3T);
            dst[rr] = (__bf16)src[k * OUTE + n];
        }
    }
}

// ---------------------------------------------------------------------------
// Phase 2+3 fused: whole MLP for a 64-row tile, bf16 MFMA, h in LDS only.
// LDS: [64][256] bf16, byte ^= ((row&7)<<4) XOR swizzle (G4).
// ---------------------------------------------------------------------------
template <int K, bool ACT>
__device__ __forceinline__ void mlp_layer(const unsigned short* lin, unsigned short* lout,
                                          const __bf16* __restrict__ Wt,
                                          const float* __restrict__ bias, int l, int w)
{
    f32x4 acc[4][4];
#pragma unroll
    for (int i = 0; i < 4; ++i)
#pragma unroll
        for (int j = 0; j < 4; ++j)
            acc[i][j] = (f32x4){0.f, 0.f, 0.f, 0.f};

    const int lr = l & 15;
    const int hi = l >> 4;
    const int kg = hi * 8;

#pragma unroll
    for (int kk = 0; kk < K; kk += 32) {
        bf16x8 af[4], bf_[4];
#pragma unroll
        for (int i = 0; i < 4; ++i) {
            const int row = i * 16 + lr;
            const int byte = row * 512 + (((kk + kg) * 2) ^ ((row & 7) << 4));
            af[i] = *reinterpret_cast<const bf16x8*>(
                reinterpret_cast<const char*>(lin) + byte);
        }
#pragma unroll
        for (int j = 0; j < 4; ++j) {
            const int n = w * 64 + j * 16 + lr;
            bf_[j] = *reinterpret_cast<const bf16x8*>(Wt + (size_t)n * K + kk + kg);
        }
#pragma unroll
        for (int i = 0; i < 4; ++i)
#pragma unroll
            for (int j = 0; j < 4; ++j)
                acc[i][j] = __builtin_amdgcn_mfma_f32_16x16x32_bf16(af[i], bf_[j],
                                                                    acc[i][j], 0, 0, 0);
    }

    float bb[4];
#pragma unroll
    for (int j = 0; j < 4; ++j)
        bb[j] = ACT ? bias[w * 64 + j * 16 + lr] : 0.f;

#pragma unroll
    for (int j = 0; j < 4; ++j) {
        const int colb = (w * 64 + j * 16 + lr) * 2;
#pragma unroll
        for (int i = 0; i < 4; ++i) {
#pragma unroll
            for (int r = 0; r < 4; ++r) {
                const int row = i * 16 + hi * 4 + r;
                float v = acc[i][j][r];
                if (ACT) {
                    v += bb[j];
                    v = v / (1.f + __expf(-v));
                }
                const int byte = row * 512 + (colb ^ ((row & 7) << 4));
                *reinterpret_cast<unsigned short*>(
                    reinterpret_cast<char*>(lout) + byte) = f2bf(v);
            }
        }
    }
}

__global__ __launch_bounds__(256) void fused_mlp_kernel(
    const float* __restrict__ summed,
    const __bf16* __restrict__ WupT, const __bf16* __restrict__ W1T,
    const __bf16* __restrict__ W2T, const __bf16* __restrict__ W3T,
    const float* __restrict__ b1, const float* __restrict__ b2,
    const float* __restrict__ b3, const float* __restrict__ Wf,
    float* __restrict__ out, int M)
{
    __shared__ __align__(16) unsigned short buf0[64 * 256];
    __shared__ __align__(16) unsigned short buf1[64 * 256];

    const int tid = threadIdx.x;
    const int l = tid & 63, w = tid >> 6;
    const int row0 = blockIdx.x * 64;

#pragma unroll
    for (int i = 0; i < 8; ++i) {
        const int id = tid + i * 256;
        const int row = id >> 5;
        const int c = (id & 31) * 4;
        float4 v = make_float4(0.f, 0.f, 0.f, 0.f);
        const int gr = row0 + row;
        if (gr < M)
            v = *reinterpret_cast<const float4*>(summed + (long long)gr * EMBED + c);
        ushort4 u = make_ushort4(f2bf(v.x), f2bf(v.y), f2bf(v.z), f2bf(v.w));
        const int byte = row * 512 + ((c * 2) ^ ((row & 7) << 4));
        *reinterpret_cast<ushort4*>(reinterpret_cast<char*>(buf0) + byte) = u;
    }
    __syncthreads();

    mlp_layer<EMBED, false>(buf0, buf1, WupT, nullptr, l, w);
    __syncthreads();
    mlp_layer<OUTE, true>(buf1, buf0, W1T, b1, l, w);
    __syncthreads();
    mlp_layer<OUTE, true>(buf0, buf1, W2T, b2, l, w);
    __syncthreads();
    mlp_layer<OUTE, true>(buf1, buf0, W3T, b3, l, w);
    __syncthreads();

    const int row = tid >> 2, q = tid & 3;
    float s = 0.f;
#pragma unroll
    for (int c = 0; c < 8; ++c) {
        const int k = q * 64 + c * 8;
        const int byte = row * 512 + ((k * 2) ^ ((row & 7) << 4));
        const bf16x8 hv = *reinterpret_cast<const bf16x8*>(
            reinterpret_cast<const char*>(buf0) + byte);
        const float4 wa = *reinterpret_cast<const float4*>(Wf + k);
        const float4 wb = *reinterpret_cast<const float4*>(Wf + k + 4);
        s += (float)hv[0] * wa.x + (float)hv[1] * wa.y +
             (float)hv[2] * wa.z + (float)hv[3] * wa.w +
             (float)hv[4] * wb.x + (float)hv[5] * wb.y +
             (float)hv[6] * wb.z + (float)hv[7] * wb.w;
    }
    s += __shfl_xor(s, 1);
    s += __shfl_xor(s, 2);
    if (q == 0 && row0 + row < M) out[row0 + row] = s;
}

extern "C" void kernel_launch(void* const* d_in, const int* in_sizes, int n_in,
                              void* d_out, int out_size, void* d_ws, size_t ws_size,
                              hipStream_t stream)
{
    const float* messages = (const float*)d_in[0];
    const float* rbf      = (const float*)d_in[1];
    const int*   idx_i    = (const int*)d_in[2];
    // d_in[3] = idx_j (unused)
    const float* W_rbf    = (const float*)d_in[4];
    const float* W_up     = (const float*)d_in[5];
    const float* W1       = (const float*)d_in[6];
    const float* b1       = (const float*)d_in[7];
    const float* W2       = (const float*)d_in[8];
    const float* b2       = (const float*)d_in[9];
    const float* W3       = (const float*)d_in[10];
    const float* b3       = (const float*)d_in[11];
    const float* Wf       = (const float*)d_in[12];
    float* out = (float*)d_out;

    const int n_edges = in_sizes[2];
    const int M = out_size;

    char* ws = (char*)d_ws;
    size_t off = 0;
    float* summed = (float*)(ws + off); off += (size_t)M * EMBED * sizeof(float);
    int* counts     = (int*)(ws + off); off += (size_t)M * sizeof(int);
    int* cursor     = (int*)(ws + off); off += (size_t)M * sizeof(int);
    int* edge_order = (int*)(ws + off); off += (size_t)n_edges * sizeof(int);
    int* pid_sorted = (int*)(ws + off); off += (size_t)n_edges * sizeof(int);
    off = (off + 255) & ~(size_t)255;
    __bf16* WupT = (__bf16*)(ws + off); off += (size_t)OUTE * EMBED * 2;
    __bf16* W1T  = (__bf16*)(ws + off); off += (size_t)OUTE * OUTE * 2;
    __bf16* W2T  = (__bf16*)(ws + off); off += (size_t)OUTE * OUTE * 2;
    __bf16* W3T  = (__bf16*)(ws + off); off += (size_t)OUTE * OUTE * 2;

    const int n4 = (int)(((size_t)M * EMBED + M) / 4);
    zero_fill_kernel<<<2048, 256, 0, stream>>>((uint4*)summed, n4);

    hist_kernel<<<4096, 256, 0, stream>>>(idx_i, counts, n_edges);
    scan_kernel<<<1, 1024, 0, stream>>>(counts, cursor, M);
    scatter_ids_kernel<<<4096, 256, 0, stream>>>(idx_i, cursor, edge_order,
                                                 pid_sorted, n_edges);
    prep_weights_kernel<<<896, 256, 0, stream>>>(W_up, W1, W2, W3, WupT, W1T, W2T, W3T);
    gated_segsum_kernel<<<2048, 256, 0, stream>>>(messages, rbf, edge_order, pid_sorted,
                                                  W_rbf, summed, n_edges);
    fused_mlp_kernel<<<(M + 63) / 64, 256, 0, stream>>>(summed, WupT, W1T, W2T, W3T,
                                                        b1, b2, b3, Wf, out, M);
}

// Round 12
// 515.844 us; speedup vs baseline: 1.0010x; 1.0010x over previous
//
#include <hip/hip_runtime.h>
#include <hip/hip_bf16.h>

#define EMBED 128
#define NRAD  16
#define OUTE  256

typedef __bf16 bf16x8 __attribute__((ext_vector_type(8)));
typedef float  f32x4  __attribute__((ext_vector_type(4)));

static __device__ __forceinline__ unsigned short f2bf(float x) {
    return __builtin_bit_cast(unsigned short, (__bf16)x);
}

// ---------------------------------------------------------------------------
// Phase 0: fast zero-fill of summed+counts (adjacent in ws).
// ---------------------------------------------------------------------------
__global__ __launch_bounds__(256) void zero_fill_kernel(uint4* __restrict__ dst, int n4)
{
    const uint4 z = {0u, 0u, 0u, 0u};
    for (int i = blockIdx.x * blockDim.x + threadIdx.x; i < n4;
         i += gridDim.x * blockDim.x)
        dst[i] = z;
}

// ---------------------------------------------------------------------------
// Phase 1a: histogram of receiving-atom indices.
// ---------------------------------------------------------------------------
__global__ __launch_bounds__(256) void hist_kernel(const int* __restrict__ idx_i,
                                                   int* __restrict__ counts, int n_edges)
{
    for (int e = blockIdx.x * blockDim.x + threadIdx.x; e < n_edges;
         e += gridDim.x * blockDim.x)
        atomicAdd(&counts[idx_i[e]], 1);
}

// ---------------------------------------------------------------------------
// Phase 1b: single-block exclusive scan of counts -> cursor (bucket starts).
// ---------------------------------------------------------------------------
__global__ __launch_bounds__(1024) void scan_kernel(const int* __restrict__ counts,
                                                    int* __restrict__ cursor, int n)
{
    __shared__ int partial[1024];
    const int tid = threadIdx.x;
    const int chunk = (n + 1023) / 1024;
    const int lo = min(tid * chunk, n), hi = min(lo + chunk, n);
    int s = 0;
    for (int i = lo; i < hi; ++i) s += counts[i];
    partial[tid] = s;
    __syncthreads();
    for (int off = 1; off < 1024; off <<= 1) {
        int v = (tid >= off) ? partial[tid - off] : 0;
        __syncthreads();
        partial[tid] += v;
        __syncthreads();
    }
    int run = (tid > 0) ? partial[tid - 1] : 0;
    for (int i = lo; i < hi; ++i) {
        cursor[i] = run;
        run += counts[i];
    }
}

// ---------------------------------------------------------------------------
// Phase 1c: scatter edge ids into CSR order; record owning particle per pos.
// ---------------------------------------------------------------------------
__global__ __launch_bounds__(256) void scatter_ids_kernel(const int* __restrict__ idx_i,
                                                          int* __restrict__ cursor,
                                                          int* __restrict__ edge_order,
                                                          int* __restrict__ pid_sorted,
                                                          int n_edges)
{
    for (int e = blockIdx.x * blockDim.x + threadIdx.x; e < n_edges;
         e += gridDim.x * blockDim.x) {
        const int i = idx_i[e];
        const int pos = atomicAdd(&cursor[i], 1);
        edge_order[pos] = e;
        pid_sorted[pos] = i;
    }
}

// ---------------------------------------------------------------------------
// Phase 1d: windowed segmented reduction, R8 pipeline:
// - window's 64 edge ids / pids held in lanes (1 coalesced load each),
//   broadcast per chunk via __shfl (VALU only -> kills the id->data hop)
// - chunk q+4's msg/rbf loads issued BEFORE chunk q's SEGSTEP (issue-early /
//   consume-late); dot for q+4 computed after SEGSTEP of q
// - ALL pipeline state in individually-NAMED scalars (R5 lesson: demotable
//   arrays -> scratch -> 200 MB phantom HBM traffic)
// ---------------------------------------------------------------------------
__device__ __forceinline__ float2 rbf_dot(float4 q0, float4 q1, float4 q2, float4 q3,
                                          const float2* w)
{
    const float rv[NRAD] = {q0.x, q0.y, q0.z, q0.w, q1.x, q1.y, q1.z, q1.w,
                            q2.x, q2.y, q2.z, q2.w, q3.x, q3.y, q3.z, q3.w};
    float tx = 0.f, ty = 0.f;
#pragma unroll
    for (int r = 0; r < NRAD; ++r) {
        tx = fmaf(rv[r], w[r].x, tx);
        ty = fmaf(rv[r], w[r].y, ty);
    }
    return make_float2(tx, ty);
}

#define SEGSTEP(P, M, T)                                                    \
    do {                                                                    \
        if ((P) != cur) {                                                   \
            if (first) {                                                    \
                atomicAdd(&summed[(long long)cur * EMBED + col], ax);       \
                atomicAdd(&summed[(long long)cur * EMBED + col + 1], ay);   \
                first = false;                                              \
            } else {                                                        \
                *reinterpret_cast<float2*>(                                 \
                    &summed[(long long)cur * EMBED + col]) =                \
                    make_float2(ax, ay);                                    \
            }                                                               \
            ax = 0.f; ay = 0.f; cur = (P);                                  \
        }                                                                   \
        ax = fmaf((M).x, (T).x, ax);                                        \
        ay = fmaf((M).y, (T).y, ay);                                        \
    } while (0)

// prefetch helpers: J must be a literal token (0..3)
#define PREF_IDS(J)                                                         \
    eN##J = __shfl(myE, qn + J, 64);                                        \
    pN##J = __shfl(myP, qn + J, 64);

#define PREF_LOAD(J)                                                        \
    mN##J = *reinterpret_cast<const float2*>(                               \
        messages + (long long)eN##J * EMBED + col);                         \
    {                                                                       \
        const float4* R_ =                                                  \
            reinterpret_cast<const float4*>(rbf + (long long)eN##J * NRAD); \
        rA##J = R_[0]; rB##J = R_[1]; rC##J = R_[2]; rD##J = R_[3];         \
    }

#define PREF_DOT(J) tN##J = rbf_dot(rA##J, rB##J, rC##J, rD##J, w);

__global__ __launch_bounds__(256, 3) void gated_segsum_kernel(
    const float* __restrict__ messages, const float* __restrict__ rbf,
    const int* __restrict__ edge_order, const int* __restrict__ pid_sorted,
    const float* __restrict__ W_rbf, float* __restrict__ summed, int n_edges)
{
    const int lane = threadIdx.x & 63;
    const int wv   = threadIdx.x >> 6;
    const int col  = lane * 2;

    float2 w[NRAD];
#pragma unroll
    for (int r = 0; r < NRAD; ++r)
        w[r] = *reinterpret_cast<const float2*>(&W_rbf[r * EMBED + col]);

    const int nwin = (n_edges + 63) >> 6;
    for (int win = blockIdx.x * 4 + wv; win < nwin; win += gridDim.x * 4) {
        const int w0 = win << 6;
        const int nq = min(n_edges - w0, 64);

        float ax = 0.f, ay = 0.f;
        bool first = true;

        if (nq == 64) {
            // -------- fast path: full window, pipelined --------
            const int myE = edge_order[w0 + lane];
            const int myP = pid_sorted[w0 + lane];
            int cur = __shfl(myP, 0, 64);

            int eN0, eN1, eN2, eN3, pN0, pN1, pN2, pN3;
            float2 mN0, mN1, mN2, mN3, tN0, tN1, tN2, tN3;
            float4 rA0, rB0, rC0, rD0, rA1, rB1, rC1, rD1;
            float4 rA2, rB2, rC2, rD2, rA3, rB3, rC3, rD3;
            float2 m0, m1, m2, m3, t0, t1, t2, t3;
            int p0, p1, p2, p3;

            // prologue: chunk 0
            int qn = 0;
            PREF_IDS(0) PREF_IDS(1) PREF_IDS(2) PREF_IDS(3)
            PREF_LOAD(0) PREF_LOAD(1) PREF_LOAD(2) PREF_LOAD(3)
            PREF_DOT(0) PREF_DOT(1) PREF_DOT(2) PREF_DOT(3)
            m0 = mN0; m1 = mN1; m2 = mN2; m3 = mN3;
            t0 = tN0; t1 = tN1; t2 = tN2; t3 = tN3;
            p0 = pN0; p1 = pN1; p2 = pN2; p3 = pN3;

            for (int q = 0; q < 64; q += 4) {
                const bool more = (q + 4) < 64;
                if (more) {
                    qn = q + 4;
                    PREF_IDS(0) PREF_IDS(1) PREF_IDS(2) PREF_IDS(3)
                    PREF_LOAD(0) PREF_LOAD(1) PREF_LOAD(2) PREF_LOAD(3)
                }
                SEGSTEP(p0, m0, t0);
                SEGSTEP(p1, m1, t1);
                SEGSTEP(p2, m2, t2);
                SEGSTEP(p3, m3, t3);
                if (more) {
                    PREF_DOT(0) PREF_DOT(1) PREF_DOT(2) PREF_DOT(3)
                    m0 = mN0; m1 = mN1; m2 = mN2; m3 = mN3;
                    t0 = tN0; t1 = tN1; t2 = tN2; t3 = tN3;
                    p0 = pN0; p1 = pN1; p2 = pN2; p3 = pN3;
                }
            }
            atomicAdd(&summed[(long long)cur * EMBED + col], ax);
            atomicAdd(&summed[(long long)cur * EMBED + col + 1], ay);
        } else {
            // -------- tail window: simple path --------
            int cur = pid_sorted[w0];
            for (int q = 0; q < nq; ++q) {
                const int b = w0 + q;
                const int e = edge_order[b];
                const int p = pid_sorted[b];
                const float2 m = *reinterpret_cast<const float2*>(
                    messages + (long long)e * EMBED + col);
                const float4* R =
                    reinterpret_cast<const float4*>(rbf + (long long)e * NRAD);
                const float2 t = rbf_dot(R[0], R[1], R[2], R[3], w);
                SEGSTEP(p, m, t);
            }
            atomicAdd(&summed[(long long)cur * EMBED + col], ax);
            atomicAdd(&summed[(long long)cur * EMBED + col + 1], ay);
        }
    }
}

// ---------------------------------------------------------------------------
// Weight prep: cast + transpose to bf16 W^T [N][K].
// ---------------------------------------------------------------------------
__global__ __launch_bounds__(256) void prep_weights_kernel(
    const float* __restrict__ Wup, const float* __restrict__ W1,
    const float* __restrict__ W2, const float* __restrict__ W3,
    __bf16* __restrict__ WupT, __bf16* __restrict__ W1T,
    __bf16* __restrict__ W2T, __bf16* __restrict__ W3T)
{
    const int total = OUTE * EMBED + 3 * OUTE * OUTE;
    for (int id = blockIdx.x * blockDim.x + threadIdx.x; id < total;
         id += gridDim.x * blockDim.x) {
        if (id < OUTE * EMBED) {
            const int n = id / EMBED, k = id % EMBED;
            WupT[id] = (__bf16)Wup[k * OUTE + n];
        } else {
            const int r = id - OUTE * EMBED;
            const int wsel = r / (OUTE * OUTE);
            const int rr = r % (OUTE * OUTE);
            const int n = rr / OUTE, k = rr % OUTE;
            const float* src = (wsel == 0) ? W1 : ((wsel == 1) ? W2 : W3);
            __bf16* dst = (wsel == 0) ? W1T : ((wsel == 1) ? W2T : W3T);
            dst[rr] = (__bf16)src[k * OUTE + n];
        }
    }
}

// ---------------------------------------------------------------------------
// Phase 2+3 fused: whole MLP for a 64-row tile, bf16 MFMA, h in LDS only.
// LDS: [64][256] bf16, byte ^= ((row&7)<<4) XOR swizzle (G4).
// ---------------------------------------------------------------------------
template <int K, bool ACT>
__device__ __forceinline__ void mlp_layer(const unsigned short* lin, unsigned short* lout,
                                          const __bf16* __restrict__ Wt,
                                          const float* __restrict__ bias, int l, int w)
{
    f32x4 acc[4][4];
#pragma unroll
    for (int i = 0; i < 4; ++i)
#pragma unroll
        for (int j = 0; j < 4; ++j)
            acc[i][j] = (f32x4){0.f, 0.f, 0.f, 0.f};

    const int lr = l & 15;
    const int hi = l >> 4;
    const int kg = hi * 8;

#pragma unroll
    for (int kk = 0; kk < K; kk += 32) {
        bf16x8 af[4], bf_[4];
#pragma unroll
        for (int i = 0; i < 4; ++i) {
            const int row = i * 16 + lr;
            const int byte = row * 512 + (((kk + kg) * 2) ^ ((row & 7) << 4));
            af[i] = *reinterpret_cast<const bf16x8*>(
                reinterpret_cast<const char*>(lin) + byte);
        }
#pragma unroll
        for (int j = 0; j < 4; ++j) {
            const int n = w * 64 + j * 16 + lr;
            bf_[j] = *reinterpret_cast<const bf16x8*>(Wt + (size_t)n * K + kk + kg);
        }
#pragma unroll
        for (int i = 0; i < 4; ++i)
#pragma unroll
            for (int j = 0; j < 4; ++j)
                acc[i][j] = __builtin_amdgcn_mfma_f32_16x16x32_bf16(af[i], bf_[j],
                                                                    acc[i][j], 0, 0, 0);
    }

    float bb[4];
#pragma unroll
    for (int j = 0; j < 4; ++j)
        bb[j] = ACT ? bias[w * 64 + j * 16 + lr] : 0.f;

#pragma unroll
    for (int j = 0; j < 4; ++j) {
        const int colb = (w * 64 + j * 16 + lr) * 2;
#pragma unroll
        for (int i = 0; i < 4; ++i) {
#pragma unroll
            for (int r = 0; r < 4; ++r) {
                const int row = i * 16 + hi * 4 + r;
                float v = acc[i][j][r];
                if (ACT) {
                    v += bb[j];
                    v = v / (1.f + __expf(-v));
                }
                const int byte = row * 512 + (colb ^ ((row & 7) << 4));
                *reinterpret_cast<unsigned short*>(
                    reinterpret_cast<char*>(lout) + byte) = f2bf(v);
            }
        }
    }
}

__global__ __launch_bounds__(256) void fused_mlp_kernel(
    const float* __restrict__ summed,
    const __bf16* __restrict__ WupT, const __bf16* __restrict__ W1T,
    const __bf16* __restrict__ W2T, const __bf16* __restrict__ W3T,
    const float* __restrict__ b1, const float* __restrict__ b2,
    const float* __restrict__ b3, const float* __restrict__ Wf,
    float* __restrict__ out, int M)
{
    __shared__ __align__(16) unsigned short buf0[64 * 256];
    __shared__ __align__(16) unsigned short buf1[64 * 256];

    const int tid = threadIdx.x;
    const int l = tid & 63, w = tid >> 6;
    const int row0 = blockIdx.x * 64;

#pragma unroll
    for (int i = 0; i < 8; ++i) {
        const int id = tid + i * 256;
        const int row = id >> 5;
        const int c = (id & 31) * 4;
        float4 v = make_float4(0.f, 0.f, 0.f, 0.f);
        const int gr = row0 + row;
        if (gr < M)
            v = *reinterpret_cast<const float4*>(summed + (long long)gr * EMBED + c);
        ushort4 u = make_ushort4(f2bf(v.x), f2bf(v.y), f2bf(v.z), f2bf(v.w));
        const int byte = row * 512 + ((c * 2) ^ ((row & 7) << 4));
        *reinterpret_cast<ushort4*>(reinterpret_cast<char*>(buf0) + byte) = u;
    }
    __syncthreads();

    mlp_layer<EMBED, false>(buf0, buf1, WupT, nullptr, l, w);
    __syncthreads();
    mlp_layer<OUTE, true>(buf1, buf0, W1T, b1, l, w);
    __syncthreads();
    mlp_layer<OUTE, true>(buf0, buf1, W2T, b2, l, w);
    __syncthreads();
    mlp_layer<OUTE, true>(buf1, buf0, W3T, b3, l, w);
    __syncthreads();

    const int row = tid >> 2, q = tid & 3;
    float s = 0.f;
#pragma unroll
    for (int c = 0; c < 8; ++c) {
        const int k = q * 64 + c * 8;
        const int byte = row * 512 + ((k * 2) ^ ((row & 7) << 4));
        const bf16x8 hv = *reinterpret_cast<const bf16x8*>(
            reinterpret_cast<const char*>(buf0) + byte);
        const float4 wa = *reinterpret_cast<const float4*>(Wf + k);
        const float4 wb = *reinterpret_cast<const float4*>(Wf + k + 4);
        s += (float)hv[0] * wa.x + (float)hv[1] * wa.y +
             (float)hv[2] * wa.z + (float)hv[3] * wa.w +
             (float)hv[4] * wb.x + (float)hv[5] * wb.y +
             (float)hv[6] * wb.z + (float)hv[7] * wb.w;
    }
    s += __shfl_xor(s, 1);
    s += __shfl_xor(s, 2);
    if (q == 0 && row0 + row < M) out[row0 + row] = s;
}

extern "C" void kernel_launch(void* const* d_in, const int* in_sizes, int n_in,
                              void* d_out, int out_size, void* d_ws, size_t ws_size,
                              hipStream_t stream)
{
    const float* messages = (const float*)d_in[0];
    const float* rbf      = (const float*)d_in[1];
    const int*   idx_i    = (const int*)d_in[2];
    // d_in[3] = idx_j (unused)
    const float* W_rbf    = (const float*)d_in[4];
    const float* W_up     = (const float*)d_in[5];
    const float* W1       = (const float*)d_in[6];
    const float* b1       = (const float*)d_in[7];
    const float* W2       = (const float*)d_in[8];
    const float* b2       = (const float*)d_in[9];
    const float* W3       = (const float*)d_in[10];
    const float* b3       = (const float*)d_in[11];
    const float* Wf       = (const float*)d_in[12];
    float* out = (float*)d_out;

    const int n_edges = in_sizes[2];
    const int M = out_size;

    char* ws = (char*)d_ws;
    size_t off = 0;
    float* summed = (float*)(ws + off); off += (size_t)M * EMBED * sizeof(float);
    int* counts     = (int*)(ws + off); off += (size_t)M * sizeof(int);
    int* cursor     = (int*)(ws + off); off += (size_t)M * sizeof(int);
    int* edge_order = (int*)(ws + off); off += (size_t)n_edges * sizeof(int);
    int* pid_sorted = (int*)(ws + off); off += (size_t)n_edges * sizeof(int);
    off = (off + 255) & ~(size_t)255;
    __bf16* WupT = (__bf16*)(ws + off); off += (size_t)OUTE * EMBED * 2;
    __bf16* W1T  = (__bf16*)(ws + off); off += (size_t)OUTE * OUTE * 2;
    __bf16* W2T  = (__bf16*)(ws + off); off += (size_t)OUTE * OUTE * 2;
    __bf16* W3T  = (__bf16*)(ws + off); off += (size_t)OUTE * OUTE * 2;

    const int n4 = (int)(((size_t)M * EMBED + M) / 4);
    zero_fill_kernel<<<2048, 256, 0, stream>>>((uint4*)summed, n4);

    hist_kernel<<<4096, 256, 0, stream>>>(idx_i, counts, n_edges);
    scan_kernel<<<1, 1024, 0, stream>>>(counts, cursor, M);
    scatter_ids_kernel<<<4096, 256, 0, stream>>>(idx_i, cursor, edge_order,
                                                 pid_sorted, n_edges);
    prep_weights_kernel<<<896, 256, 0, stream>>>(W_up, W1, W2, W3, WupT, W1T, W2T, W3T);
    gated_segsum_kernel<<<2048, 256, 0, stream>>>(messages, rbf, edge_order, pid_sorted,
                                                  W_rbf, summed, n_edges);
    fused_mlp_kernel<<<(M + 63) / 64, 256, 0, stream>>>(summed, WupT, W1T, W2T, W3T,
                                                        b1, b2, b3, Wf, out, M);
}

// Round 13
// 454.861 us; speedup vs baseline: 1.1352x; 1.1341x over previous
//
#include <hip/hip_runtime.h>
#include <hip/hip_bf16.h>

#define EMBED 128
#define NRAD  16
#define OUTE  256

typedef __bf16 bf16x8 __attribute__((ext_vector_type(8)));
typedef float  f32x4  __attribute__((ext_vector_type(4)));

static __device__ __forceinline__ unsigned short f2bf(float x) {
    return __builtin_bit_cast(unsigned short, (__bf16)x);
}

// broadcast float from (uniform) lane L via v_readlane — no LDS, no latency
#define RLF(X, L) __builtin_bit_cast(float, \
    __builtin_amdgcn_readlane(__builtin_bit_cast(int, (X)), (L)))

// ---------------------------------------------------------------------------
// Phase 0: fast zero-fill of summed+counts (adjacent in ws).
// ---------------------------------------------------------------------------
__global__ __launch_bounds__(256) void zero_fill_kernel(uint4* __restrict__ dst, int n4)
{
    const uint4 z = {0u, 0u, 0u, 0u};
    for (int i = blockIdx.x * blockDim.x + threadIdx.x; i < n4;
         i += gridDim.x * blockDim.x)
        dst[i] = z;
}

// ---------------------------------------------------------------------------
// Phase 1a: histogram of receiving-atom indices.
// ---------------------------------------------------------------------------
__global__ __launch_bounds__(256) void hist_kernel(const int* __restrict__ idx_i,
                                                   int* __restrict__ counts, int n_edges)
{
    for (int e = blockIdx.x * blockDim.x + threadIdx.x; e < n_edges;
         e += gridDim.x * blockDim.x)
        atomicAdd(&counts[idx_i[e]], 1);
}

// ---------------------------------------------------------------------------
// Phase 1b: single-block exclusive scan of counts -> cursor (bucket starts).
// ---------------------------------------------------------------------------
__global__ __launch_bounds__(1024) void scan_kernel(const int* __restrict__ counts,
                                                    int* __restrict__ cursor, int n)
{
    __shared__ int partial[1024];
    const int tid = threadIdx.x;
    const int chunk = (n + 1023) / 1024;
    const int lo = min(tid * chunk, n), hi = min(lo + chunk, n);
    int s = 0;
    for (int i = lo; i < hi; ++i) s += counts[i];
    partial[tid] = s;
    __syncthreads();
    for (int off = 1; off < 1024; off <<= 1) {
        int v = (tid >= off) ? partial[tid - off] : 0;
        __syncthreads();
        partial[tid] += v;
        __syncthreads();
    }
    int run = (tid > 0) ? partial[tid - 1] : 0;
    for (int i = lo; i < hi; ++i) {
        cursor[i] = run;
        run += counts[i];
    }
}

// ---------------------------------------------------------------------------
// Phase 1c: scatter (edge id, particle id) as ONE int2 per CSR position
// (R12 lesson: two separate 4-B random stores double the 64B-line RMWs).
// ---------------------------------------------------------------------------
__global__ __launch_bounds__(256) void scatter_ids_kernel(const int* __restrict__ idx_i,
                                                          int* __restrict__ cursor,
                                                          int2* __restrict__ eid_pid,
                                                          int n_edges)
{
    for (int e = blockIdx.x * blockDim.x + threadIdx.x; e < n_edges;
         e += gridDim.x * blockDim.x) {
        const int i = idx_i[e];
        const int pos = atomicAdd(&cursor[i], 1);
        eid_pid[pos] = make_int2(e, i);
    }
}

// ---------------------------------------------------------------------------
// Phase 1d: windowed segmented reduction, v3:
// - one coalesced int2 load gives each lane its window edge/particle id
// - each lane loads ITS OWN edge's rbf row (4x float4, coalesced-ish burst,
//   once per window); consume-time broadcast via v_readlane (pure VALU,
//   zero latency) -> NO per-chunk rbf memory dependence (R8's residual stall)
// - msg loads stay in the proven 2-chunk-ahead NAMED-SCALAR pipeline
//   (R5 lesson: demotable arrays -> scratch)
// ---------------------------------------------------------------------------
#define SEGSTEP(P, M, T)                                                    \
    do {                                                                    \
        if ((P) != cur) {                                                   \
            if (first) {                                                    \
                atomicAdd(&summed[(long long)cur * EMBED + col], ax);       \
                atomicAdd(&summed[(long long)cur * EMBED + col + 1], ay);   \
                first = false;                                              \
            } else {                                                        \
                *reinterpret_cast<float2*>(                                 \
                    &summed[(long long)cur * EMBED + col]) =                \
                    make_float2(ax, ay);                                    \
            }                                                               \
            ax = 0.f; ay = 0.f; cur = (P);                                  \
        }                                                                   \
        ax = fmaf((M).x, (T).x, ax);                                        \
        ay = fmaf((M).y, (T).y, ay);                                        \
    } while (0)

// issue msg loads for the 4 edges at window positions QPOS..QPOS+3 into
// named float2s S0..S3
#define MSG_ISSUE(S, QPOS)                                                  \
    {                                                                       \
        const int eT0 = __shfl(myE, (QPOS) + 0, 64);                        \
        const int eT1 = __shfl(myE, (QPOS) + 1, 64);                        \
        const int eT2 = __shfl(myE, (QPOS) + 2, 64);                        \
        const int eT3 = __shfl(myE, (QPOS) + 3, 64);                        \
        S##0 = *reinterpret_cast<const float2*>(                            \
            messages + (long long)eT0 * EMBED + col);                       \
        S##1 = *reinterpret_cast<const float2*>(                            \
            messages + (long long)eT1 * EMBED + col);                       \
        S##2 = *reinterpret_cast<const float2*>(                            \
            messages + (long long)eT2 * EMBED + col);                       \
        S##3 = *reinterpret_cast<const float2*>(                            \
            messages + (long long)eT3 * EMBED + col);                       \
    }

// dot( rbf[edge at window pos L], W_rbf[:, col..col+1] ) via readlane
#define DOT_EDGE(TX, TY, L)                                                      \
    {                                                                            \
        float v_;                                                                \
        TX = 0.f; TY = 0.f;                                                      \
        v_ = RLF(ra.x, L); TX = fmaf(v_, w[0].x, TX);  TY = fmaf(v_, w[0].y, TY);  \
        v_ = RLF(ra.y, L); TX = fmaf(v_, w[1].x, TX);  TY = fmaf(v_, w[1].y, TY);  \
        v_ = RLF(ra.z, L); TX = fmaf(v_, w[2].x, TX);  TY = fmaf(v_, w[2].y, TY);  \
        v_ = RLF(ra.w, L); TX = fmaf(v_, w[3].x, TX);  TY = fmaf(v_, w[3].y, TY);  \
        v_ = RLF(rb.x, L); TX = fmaf(v_, w[4].x, TX);  TY = fmaf(v_, w[4].y, TY);  \
        v_ = RLF(rb.y, L); TX = fmaf(v_, w[5].x, TX);  TY = fmaf(v_, w[5].y, TY);  \
        v_ = RLF(rb.z, L); TX = fmaf(v_, w[6].x, TX);  TY = fmaf(v_, w[6].y, TY);  \
        v_ = RLF(rb.w, L); TX = fmaf(v_, w[7].x, TX);  TY = fmaf(v_, w[7].y, TY);  \
        v_ = RLF(rc.x, L); TX = fmaf(v_, w[8].x, TX);  TY = fmaf(v_, w[8].y, TY);  \
        v_ = RLF(rc.y, L); TX = fmaf(v_, w[9].x, TX);  TY = fmaf(v_, w[9].y, TY);  \
        v_ = RLF(rc.z, L); TX = fmaf(v_, w[10].x, TX); TY = fmaf(v_, w[10].y, TY); \
        v_ = RLF(rc.w, L); TX = fmaf(v_, w[11].x, TX); TY = fmaf(v_, w[11].y, TY); \
        v_ = RLF(rd.x, L); TX = fmaf(v_, w[12].x, TX); TY = fmaf(v_, w[12].y, TY); \
        v_ = RLF(rd.y, L); TX = fmaf(v_, w[13].x, TX); TY = fmaf(v_, w[13].y, TY); \
        v_ = RLF(rd.z, L); TX = fmaf(v_, w[14].x, TX); TY = fmaf(v_, w[14].y, TY); \
        v_ = RLF(rd.w, L); TX = fmaf(v_, w[15].x, TX); TY = fmaf(v_, w[15].y, TY); \
    }

__global__ __launch_bounds__(256, 4) void gated_segsum_kernel(
    const float* __restrict__ messages, const float* __restrict__ rbf,
    const int2* __restrict__ eid_pid,
    const float* __restrict__ W_rbf, float* __restrict__ summed, int n_edges)
{
    const int lane = threadIdx.x & 63;
    const int wv   = threadIdx.x >> 6;
    const int col  = lane * 2;

    float2 w[NRAD];
#pragma unroll
    for (int r = 0; r < NRAD; ++r)
        w[r] = *reinterpret_cast<const float2*>(&W_rbf[r * EMBED + col]);

    const int nwin = (n_edges + 63) >> 6;
    for (int win = blockIdx.x * 4 + wv; win < nwin; win += gridDim.x * 4) {
        const int w0 = win << 6;
        const int nq = min(n_edges - w0, 64);

        float ax = 0.f, ay = 0.f;
        bool first = true;

        if (nq == 64) {
            // ---- fast path: full window ----
            const int2 ep = eid_pid[w0 + lane];
            const int myE = ep.x;
            const int myP = ep.y;
            int cur = __builtin_amdgcn_readlane(myP, 0);

            // lane-owned rbf row (stays resident the whole window)
            const float4* R = reinterpret_cast<const float4*>(rbf + (long long)myE * NRAD);
            const float4 ra = R[0], rb = R[1], rc = R[2], rd = R[3];

            float2 cA0, cA1, cA2, cA3, cB0, cB1, cB2, cB3, cC0, cC1, cC2, cC3;
            MSG_ISSUE(cA, 0)
            MSG_ISSUE(cB, 4)

            for (int q = 0; q < 16; ++q) {
                if (q < 14) { MSG_ISSUE(cC, (q + 2) * 4) }

                const int base = q * 4;
                float t0x, t0y, t1x, t1y, t2x, t2y, t3x, t3y;
                DOT_EDGE(t0x, t0y, base + 0)
                DOT_EDGE(t1x, t1y, base + 1)
                DOT_EDGE(t2x, t2y, base + 2)
                DOT_EDGE(t3x, t3y, base + 3)
                const int p0 = __builtin_amdgcn_readlane(myP, base + 0);
                const int p1 = __builtin_amdgcn_readlane(myP, base + 1);
                const int p2 = __builtin_amdgcn_readlane(myP, base + 2);
                const int p3 = __builtin_amdgcn_readlane(myP, base + 3);
                const float2 t0 = make_float2(t0x, t0y);
                const float2 t1 = make_float2(t1x, t1y);
                const float2 t2 = make_float2(t2x, t2y);
                const float2 t3 = make_float2(t3x, t3y);

                SEGSTEP(p0, cA0, t0);
                SEGSTEP(p1, cA1, t1);
                SEGSTEP(p2, cA2, t2);
                SEGSTEP(p3, cA3, t3);

                cA0 = cB0; cA1 = cB1; cA2 = cB2; cA3 = cB3;
                cB0 = cC0; cB1 = cC1; cB2 = cC2; cB3 = cC3;
            }
            atomicAdd(&summed[(long long)cur * EMBED + col], ax);
            atomicAdd(&summed[(long long)cur * EMBED + col + 1], ay);
        } else {
            // ---- tail window: simple path ----
            int cur = eid_pid[w0].y;
            for (int q = 0; q < nq; ++q) {
                const int2 ep = eid_pid[w0 + q];
                const float2 m = *reinterpret_cast<const float2*>(
                    messages + (long long)ep.x * EMBED + col);
                const float4* R =
                    reinterpret_cast<const float4*>(rbf + (long long)ep.x * NRAD);
                const float4 q0 = R[0], q1 = R[1], q2 = R[2], q3 = R[3];
                const float rv[NRAD] = {q0.x, q0.y, q0.z, q0.w, q1.x, q1.y, q1.z, q1.w,
                                        q2.x, q2.y, q2.z, q2.w, q3.x, q3.y, q3.z, q3.w};
                float tx = 0.f, ty = 0.f;
#pragma unroll
                for (int r = 0; r < NRAD; ++r) {
                    tx = fmaf(rv[r], w[r].x, tx);
                    ty = fmaf(rv[r], w[r].y, ty);
                }
                const float2 t = make_float2(tx, ty);
                SEGSTEP(ep.y, m, t);
            }
            atomicAdd(&summed[(long long)cur * EMBED + col], ax);
            atomicAdd(&summed[(long long)cur * EMBED + col + 1], ay);
        }
    }
}

// ---------------------------------------------------------------------------
// Weight prep: cast + transpose to bf16 W^T [N][K].
// ---------------------------------------------------------------------------
__global__ __launch_bounds__(256) void prep_weights_kernel(
    const float* __restrict__ Wup, const float* __restrict__ W1,
    const float* __restrict__ W2, const float* __restrict__ W3,
    __bf16* __restrict__ WupT, __bf16* __restrict__ W1T,
    __bf16* __restrict__ W2T, __bf16* __restrict__ W3T)
{
    const int total = OUTE * EMBED + 3 * OUTE * OUTE;
    for (int id = blockIdx.x * blockDim.x + threadIdx.x; id < total;
         id += gridDim.x * blockDim.x) {
        if (id < OUTE * EMBED) {
            const int n = id / EMBED, k = id % EMBED;
            WupT[id] = (__bf16)Wup[k * OUTE + n];
        } else {
            const int r = id - OUTE * EMBED;
            const int wsel = r / (OUTE * OUTE);
            const int rr = r % (OUTE * OUTE);
            const int n = rr / OUTE, k = rr % OUTE;
            const float* src = (wsel == 0) ? W1 : ((wsel == 1) ? W2 : W3);
            __bf16* dst = (wsel == 0) ? W1T : ((wsel == 1) ? W2T : W3T);
            dst[rr] = (__bf16)src[k * OUTE + n];
        }
    }
}

// ---------------------------------------------------------------------------
// Phase 2+3 fused: whole MLP for a 64-row tile, bf16 MFMA, h in LDS only.
// LDS: [64][256] bf16, byte ^= ((row&7)<<4) XOR swizzle (G4).
// ---------------------------------------------------------------------------
template <int K, bool ACT>
__device__ __forceinline__ void mlp_layer(const unsigned short* lin, unsigned short* lout,
                                          const __bf16* __restrict__ Wt,
                                          const float* __restrict__ bias, int l, int w)
{
    f32x4 acc[4][4];
#pragma unroll
    for (int i = 0; i < 4; ++i)
#pragma unroll
        for (int j = 0; j < 4; ++j)
            acc[i][j] = (f32x4){0.f, 0.f, 0.f, 0.f};

    const int lr = l & 15;
    const int hi = l >> 4;
    const int kg = hi * 8;

#pragma unroll
    for (int kk = 0; kk < K; kk += 32) {
        bf16x8 af[4], bf_[4];
#pragma unroll
        for (int i = 0; i < 4; ++i) {
            const int row = i * 16 + lr;
            const int byte = row * 512 + (((kk + kg) * 2) ^ ((row & 7) << 4));
            af[i] = *reinterpret_cast<const bf16x8*>(
                reinterpret_cast<const char*>(lin) + byte);
        }
#pragma unroll
        for (int j = 0; j < 4; ++j) {
            const int n = w * 64 + j * 16 + lr;
            bf_[j] = *reinterpret_cast<const bf16x8*>(Wt + (size_t)n * K + kk + kg);
        }
#pragma unroll
        for (int i = 0; i < 4; ++i)
#pragma unroll
            for (int j = 0; j < 4; ++j)
                acc[i][j] = __builtin_amdgcn_mfma_f32_16x16x32_bf16(af[i], bf_[j],
                                                                    acc[i][j], 0, 0, 0);
    }

    float bb[4];
#pragma unroll
    for (int j = 0; j < 4; ++j)
        bb[j] = ACT ? bias[w * 64 + j * 16 + lr] : 0.f;

#pragma unroll
    for (int j = 0; j < 4; ++j) {
        const int colb = (w * 64 + j * 16 + lr) * 2;
#pragma unroll
        for (int i = 0; i < 4; ++i) {
#pragma unroll
            for (int r = 0; r < 4; ++r) {
                const int row = i * 16 + hi * 4 + r;
                float v = acc[i][j][r];
                if (ACT) {
                    v += bb[j];
                    v = v / (1.f + __expf(-v));
                }
                const int byte = row * 512 + (colb ^ ((row & 7) << 4));
                *reinterpret_cast<unsigned short*>(
                    reinterpret_cast<char*>(lout) + byte) = f2bf(v);
            }
        }
    }
}

__global__ __launch_bounds__(256) void fused_mlp_kernel(
    const float* __restrict__ summed,
    const __bf16* __restrict__ WupT, const __bf16* __restrict__ W1T,
    const __bf16* __restrict__ W2T, const __bf16* __restrict__ W3T,
    const float* __restrict__ b1, const float* __restrict__ b2,
    const float* __restrict__ b3, const float* __restrict__ Wf,
    float* __restrict__ out, int M)
{
    __shared__ __align__(16) unsigned short buf0[64 * 256];
    __shared__ __align__(16) unsigned short buf1[64 * 256];

    const int tid = threadIdx.x;
    const int l = tid & 63, w = tid >> 6;
    const int row0 = blockIdx.x * 64;

#pragma unroll
    for (int i = 0; i < 8; ++i) {
        const int id = tid + i * 256;
        const int row = id >> 5;
        const int c = (id & 31) * 4;
        float4 v = make_float4(0.f, 0.f, 0.f, 0.f);
        const int gr = row0 + row;
        if (gr < M)
            v = *reinterpret_cast<const float4*>(summed + (long long)gr * EMBED + c);
        ushort4 u = make_ushort4(f2bf(v.x), f2bf(v.y), f2bf(v.z), f2bf(v.w));
        const int byte = row * 512 + ((c * 2) ^ ((row & 7) << 4));
        *reinterpret_cast<ushort4*>(reinterpret_cast<char*>(buf0) + byte) = u;
    }
    __syncthreads();

    mlp_layer<EMBED, false>(buf0, buf1, WupT, nullptr, l, w);
    __syncthreads();
    mlp_layer<OUTE, true>(buf1, buf0, W1T, b1, l, w);
    __syncthreads();
    mlp_layer<OUTE, true>(buf0, buf1, W2T, b2, l, w);
    __syncthreads();
    mlp_layer<OUTE, true>(buf1, buf0, W3T, b3, l, w);
    __syncthreads();

    const int row = tid >> 2, q = tid & 3;
    float s = 0.f;
#pragma unroll
    for (int c = 0; c < 8; ++c) {
        const int k = q * 64 + c * 8;
        const int byte = row * 512 + ((k * 2) ^ ((row & 7) << 4));
        const bf16x8 hv = *reinterpret_cast<const bf16x8*>(
            reinterpret_cast<const char*>(buf0) + byte);
        const float4 wa = *reinterpret_cast<const float4*>(Wf + k);
        const float4 wb = *reinterpret_cast<const float4*>(Wf + k + 4);
        s += (float)hv[0] * wa.x + (float)hv[1] * wa.y +
             (float)hv[2] * wa.z + (float)hv[3] * wa.w +
             (float)hv[4] * wb.x + (float)hv[5] * wb.y +
             (float)hv[6] * wb.z + (float)hv[7] * wb.w;
    }
    s += __shfl_xor(s, 1);
    s += __shfl_xor(s, 2);
    if (q == 0 && row0 + row < M) out[row0 + row] = s;
}

extern "C" void kernel_launch(void* const* d_in, const int* in_sizes, int n_in,
                              void* d_out, int out_size, void* d_ws, size_t ws_size,
                              hipStream_t stream)
{
    const float* messages = (const float*)d_in[0];
    const float* rbf      = (const float*)d_in[1];
    const int*   idx_i    = (const int*)d_in[2];
    // d_in[3] = idx_j (unused)
    const float* W_rbf    = (const float*)d_in[4];
    const float* W_up     = (const float*)d_in[5];
    const float* W1       = (const float*)d_in[6];
    const float* b1       = (const float*)d_in[7];
    const float* W2       = (const float*)d_in[8];
    const float* b2       = (const float*)d_in[9];
    const float* W3       = (const float*)d_in[10];
    const float* b3       = (const float*)d_in[11];
    const float* Wf       = (const float*)d_in[12];
    float* out = (float*)d_out;

    const int n_edges = in_sizes[2];
    const int M = out_size;

    char* ws = (char*)d_ws;
    size_t off = 0;
    float* summed = (float*)(ws + off); off += (size_t)M * EMBED * sizeof(float);
    int* counts     = (int*)(ws + off); off += (size_t)M * sizeof(int);
    int* cursor     = (int*)(ws + off); off += (size_t)M * sizeof(int);
    off = (off + 7) & ~(size_t)7;   // int2 alignment
    int2* eid_pid   = (int2*)(ws + off); off += (size_t)n_edges * sizeof(int2);
    off = (off + 255) & ~(size_t)255;
    __bf16* WupT = (__bf16*)(ws + off); off += (size_t)OUTE * EMBED * 2;
    __bf16* W1T  = (__bf16*)(ws + off); off += (size_t)OUTE * OUTE * 2;
    __bf16* W2T  = (__bf16*)(ws + off); off += (size_t)OUTE * OUTE * 2;
    __bf16* W3T  = (__bf16*)(ws + off); off += (size_t)OUTE * OUTE * 2;

    const int n4 = (int)(((size_t)M * EMBED + M) / 4);
    zero_fill_kernel<<<2048, 256, 0, stream>>>((uint4*)summed, n4);

    hist_kernel<<<4096, 256, 0, stream>>>(idx_i, counts, n_edges);
    scan_kernel<<<1, 1024, 0, stream>>>(counts, cursor, M);
    scatter_ids_kernel<<<4096, 256, 0, stream>>>(idx_i, cursor, eid_pid, n_edges);
    prep_weights_kernel<<<896, 256, 0, stream>>>(W_up, W1, W2, W3, WupT, W1T, W2T, W3T);
    gated_segsum_kernel<<<2048, 256, 0, stream>>>(messages, rbf, eid_pid,
                                                  W_rbf, summed, n_edges);
    fused_mlp_kernel<<<(M + 63) / 64, 256, 0, stream>>>(summed, WupT, W1T, W2T, W3T,
                                                        b1, b2, b3, Wf, out, M);
}